// Round 7
// baseline (880.197 us; speedup 1.0000x reference)
//
#include <hip/hip_runtime.h>

#define TSTEPS 1023
#define GAMMA  (0.01f / 32.0f)   // LR * dL/dy scale: 2/(64*2) folded
#define EPSV   1e-5f

// workspace layout (float offsets)
#define WS_HS 0       // 64*64 hs table
#define WS_G  4096    // 64*64 gram
#define WS_Z0 8192    // 64*16 initial Ztilde = hs@w1 + b1

typedef float v2f __attribute__((ext_vector_type(2)));
typedef unsigned int v2u __attribute__((ext_vector_type(2)));

template<int CTRL>
__device__ __forceinline__ float dppmov(float x) {
    return __int_as_float(__builtin_amdgcn_update_dpp(0, __float_as_int(x), CTRL, 0xF, 0xF, true));
}
// sum over {l, l^16} / {l, l^32} via permlane swaps (VALU, no DS)
__device__ __forceinline__ float sum_x16(float x) {
    v2u r = __builtin_amdgcn_permlane16_swap(__float_as_uint(x), __float_as_uint(x), false, false);
    return __uint_as_float(r[0]) + __uint_as_float(r[1]);
}
__device__ __forceinline__ float sum_x32(float x) {
    v2u r = __builtin_amdgcn_permlane32_swap(__float_as_uint(x), __float_as_uint(x), false, false);
    return __uint_as_float(r[0]) + __uint_as_float(r[1]);
}

// ---------------- kernel A: hs table (per-token embed->FFN->LN) ----------------
__global__ void hs_kernel(const float* __restrict__ embed,
                          const float* __restrict__ ffw1, const float* __restrict__ ffb1,
                          const float* __restrict__ ffw2, const float* __restrict__ ffb2,
                          const float* __restrict__ lng,  const float* __restrict__ lnb,
                          float* __restrict__ ws) {
    __shared__ float e[64];
    __shared__ float a1[128];
    int w = blockIdx.x;
    int tid = threadIdx.x;
    if (tid < 64) e[tid] = embed[w * 64 + tid];
    __syncthreads();
    float z1 = ffb1[tid];
    for (int x = 0; x < 64; ++x) z1 += e[x] * ffw1[x * 128 + tid];
    a1[tid] = fmaxf(z1, 0.0f);
    __syncthreads();
    if (tid < 64) {
        float f = ffb2[tid];
        for (int i = 0; i < 128; ++i) f += a1[i] * ffw2[i * 64 + tid];
        float hv = e[tid] + f;
        float s = hv;
#pragma unroll
        for (int m = 32; m >= 1; m >>= 1) s += __shfl_xor(s, m);
        float mu = s * (1.0f / 64.0f);
        float dv = hv - mu;
        float vs = dv * dv;
#pragma unroll
        for (int m = 32; m >= 1; m >>= 1) vs += __shfl_xor(vs, m);
        float rstd = 1.0f / sqrtf(vs * (1.0f / 64.0f) + EPSV);
        ws[WS_HS + w * 64 + tid] = dv * rstd * lng[tid] + lnb[tid];
    }
}

// ---------------- kernel B: Gram matrix + Ztilde0 ----------------
__global__ void gz_kernel(const float* __restrict__ w1, const float* __restrict__ b1,
                          float* __restrict__ ws) {
    __shared__ float row[64];
    int w = blockIdx.x, tid = threadIdx.x;
    row[tid] = ws[WS_HS + w * 64 + tid];
    __syncthreads();
    float g = 0.0f;
    for (int x = 0; x < 64; ++x) g += row[x] * ws[WS_HS + tid * 64 + x];
    ws[WS_G + w * 64 + tid] = g;
    if (tid < 16) {
        float z = b1[tid];
        for (int x = 0; x < 64; ++x) z += row[x] * w1[x * 16 + tid];
        ws[WS_Z0 + w * 16 + tid] = z;
    }
}

// scalar view of packed v2f array
#define PV(arr, j) (((j) & 1) ? arr[(j) >> 1].y : arr[(j) >> 1].x)

// ---------------- main kernel: 8 independent waves per block ----------------
// 32 blocks x 512 threads; wave w of block B runs batch B*8+w (no barriers,
// no cross-wave data). 2 waves per SIMD -> issue-slot interleave experiment.
// Per wave: lane h owns W2[:,h], b2_h, Ztilde row h (regs + LDS mirror in a
// per-wave region). hs/G/seq are read from GLOBAL (L1/L2-resident), always
// issued one full iteration before consumption. Z writeback is masked to the
// two rows that can be read next (tk(t+2) and, for the peel, the query row).
__launch_bounds__(512, 2)
__global__ void ttt_kernel(const int* __restrict__ seq,
                           const float* __restrict__ w2, const float* __restrict__ b2i,
                           const float* __restrict__ outw, const float* __restrict__ outb,
                           const float* __restrict__ ws, float* __restrict__ out) {
    __shared__ __align__(16) float Zs[8][64 * 20];   // per-wave Ztilde mirror
    __shared__ float ctxs[8][64];

    const int wv   = threadIdx.x >> 6;
    const int lane = threadIdx.x & 63;
    const int b    = blockIdx.x * 8 + wv;

    const int*   sqg = seq + b * 2048;
    const float* hsg = ws + WS_HS;
    const float* Gg  = ws + WS_G;
    float*       Zw  = Zs[wv];

    v2f W2p[8], Zrp[8], z2[8];
#pragma unroll
    for (int i = 0; i < 8; ++i) {
        v2f w;
        w.x = w2[(2 * i) * 64 + lane];
        w.y = w2[(2 * i + 1) * 64 + lane];
        W2p[i] = w;
    }
    float b2v = b2i[lane];
    {
        const float4* z0 = (const float4*)(ws + WS_Z0 + lane * 16);
        float4 u0 = z0[0], u1 = z0[1], u2 = z0[2], u3 = z0[3];
        Zrp[0] = {u0.x, u0.y}; Zrp[1] = {u0.z, u0.w};
        Zrp[2] = {u1.x, u1.y}; Zrp[3] = {u1.z, u1.w};
        Zrp[4] = {u2.x, u2.y}; Zrp[5] = {u2.z, u2.w};
        Zrp[6] = {u3.x, u3.y}; Zrp[7] = {u3.z, u3.w};
        float4* zr = (float4*)(Zw + lane * 20);      // stage ALL rows once
        zr[0] = u0; zr[1] = u1; zr[2] = u2; zr[3] = u3;
    }

    int tk  = sqg[0];
    int tv0 = sqg[1];
    {   // z2 init: in-order DS guarantees staging writes are visible
        const float4* zp = (const float4*)(Zw + tk * 20);
        float4 u0 = zp[0], u1 = zp[1], u2 = zp[2], u3 = zp[3];
        z2[0] = {u0.x, u0.y}; z2[1] = {u0.z, u0.w};
        z2[2] = {u1.x, u1.y}; z2[3] = {u1.z, u1.w};
        z2[4] = {u2.x, u2.y}; z2[5] = {u2.z, u2.w};
        z2[6] = {u3.x, u3.y}; z2[7] = {u3.z, u3.w};
    }
    float vv = hsg[tv0 * 64 + lane];

    int2 pairT  = *(const int2*)(sqg + 2);
    int2 pairT1 = *(const int2*)(sqg + 4);
    float crP = GAMMA * Gg[tk * 64 + lane]    + GAMMA;   // step-0 coefficients
    float czP = GAMMA * Gg[tk * 64 + pairT.x] + GAMMA;

    const bool bl0 = (lane & 1) != 0;
    const bool bl1 = (lane & 2) != 0;

    // main loop: steps 0..1021 (last step peeled)
#pragma unroll 2
    for (int t = 0; t < TSTEPS - 1; ++t) {
        const int tkn = pairT.x;                 // tk(t+1)
        const int tvn = pairT.y;                 // tv(t+1)

        // ---- LDS read (reg address, consumed late this iter) ----
        const float4* zp = (const float4*)(Zw + tkn * 20);   // Ztilde_t[tk(t+1)]
        const float4 e0 = zp[0], e1 = zp[1], e2 = zp[2], e3 = zp[3];

        // ---- global prefetches for NEXT iter (full-iter flight time) ----
        const float vnext = hsg[tvn * 64 + lane];                    // vv(t+1)
        const float crN = GAMMA * Gg[tkn * 64 + lane]      + GAMMA;  // cr(t+1)
        const float czN = GAMMA * Gg[tkn * 64 + pairT1.x]  + GAMMA;  // cz(t+1)
        const int   lbase = (t < TSTEPS - 3) ? (2 * t + 6) : 2046;
        const int2  pairT2 = *(const int2*)(sqg + lbase);            // pair(t+2)

        // ---- forward (packed) ----
        const v2f zero2 = {0.0f, 0.0f};
        v2f a2[8];
#pragma unroll
        for (int i = 0; i < 8; ++i) a2[i] = __builtin_elementwise_max(z2[i], zero2);
        v2f acc0 = a2[0] * W2p[0] + a2[1] * W2p[1];
        v2f acc1 = a2[2] * W2p[2] + a2[3] * W2p[3];
        v2f acc2 = a2[4] * W2p[4] + a2[5] * W2p[5];
        v2f acc3 = a2[6] * W2p[6] + a2[7] * W2p[7];
        v2f accv = (acc0 + acc1) + (acc2 + acc3);
        const float y = b2v + accv.x + accv.y;
        const float d = y - vv;

        // ---- p (pre-update W2) + local W2/b2 update ----
        const v2f d2 = {d, d};
        v2f p2[8];
#pragma unroll
        for (int i = 0; i < 8; ++i) p2[i] = W2p[i] * d2;
        const float sd = GAMMA * d;
        const v2f sd2 = {sd, sd};
        b2v -= sd;
#pragma unroll
        for (int i = 0; i < 8; ++i) W2p[i] = W2p[i] - sd2 * a2[i];

        // ---- reduction (all-VALU), keep/give folds ----
        float q[8];
#pragma unroll
        for (int j = 0; j < 8; ++j) {
            const float keep = bl0 ? PV(p2, j + 8) : PV(p2, j);
            const float give = bl0 ? PV(p2, j)     : PV(p2, j + 8);
            q[j] = keep + dppmov<0xB1>(give);       // quad_perm [1,0,3,2] (xor1)
        }
        float r[4];
#pragma unroll
        for (int j = 0; j < 4; ++j) {
            const float keep = bl1 ? q[j + 4] : q[j];
            const float give = bl1 ? q[j]     : q[j + 4];
            r[j] = keep + dppmov<0x4E>(give);       // quad_perm [2,3,0,1] (xor2)
        }
        float tot[4];
#pragma unroll
        for (int j = 0; j < 4; ++j) {
            float x = r[j] + dppmov<0x124>(r[j]);   // row_ror:4
            x = x + dppmov<0x128>(x);               // row_ror:8
            x = sum_x16(x);
            tot[j] = sum_x32(x);
        }
        // tot[jj] = da[jj + 4*b1 + 8*b0] replicated across quads

        // ---- mask in encoded space, then quad_perm broadcast ----
        float totm[4];
#pragma unroll
        for (int jj = 0; jj < 4; ++jj) {
            const float s0 = bl1 ? PV(a2, jj + 4)  : PV(a2, jj);
            const float s1 = bl1 ? PV(a2, jj + 12) : PV(a2, jj + 8);
            const float aenc = bl0 ? s1 : s0;
            totm[jj] = (aenc > 0.0f) ? tot[jj] : 0.0f;
        }
        float dz[16];
        dz[0]  = dppmov<0x00>(totm[0]);  dz[1]  = dppmov<0x00>(totm[1]);
        dz[2]  = dppmov<0x00>(totm[2]);  dz[3]  = dppmov<0x00>(totm[3]);
        dz[4]  = dppmov<0xAA>(totm[0]);  dz[5]  = dppmov<0xAA>(totm[1]);
        dz[6]  = dppmov<0xAA>(totm[2]);  dz[7]  = dppmov<0xAA>(totm[3]);
        dz[8]  = dppmov<0x55>(totm[0]);  dz[9]  = dppmov<0x55>(totm[1]);
        dz[10] = dppmov<0x55>(totm[2]);  dz[11] = dppmov<0x55>(totm[3]);
        dz[12] = dppmov<0xFF>(totm[0]);  dz[13] = dppmov<0xFF>(totm[1]);
        dz[14] = dppmov<0xFF>(totm[2]);  dz[15] = dppmov<0xFF>(totm[3]);

        v2f dz2[8];
#pragma unroll
        for (int i = 0; i < 8; ++i) dz2[i] = {dz[2 * i], dz[2 * i + 1]};

        // ---- apply ----
        const v2f cr2 = {crP, crP}, cz2 = {czP, czP};
        const v2f zq2[8] = { {e0.x, e0.y}, {e0.z, e0.w}, {e1.x, e1.y}, {e1.z, e1.w},
                             {e2.x, e2.y}, {e2.z, e2.w}, {e3.x, e3.y}, {e3.z, e3.w} };
#pragma unroll
        for (int i = 0; i < 8; ++i) {
            Zrp[i] = Zrp[i] - cr2 * dz2[i];
            z2[i]  = zq2[i] - cz2 * dz2[i];
        }

        // ---- masked writeback: only rows readable next (tk(t+2)) or by peel ----
        if (lane == pairT1.x || lane == pairT1.y) {
            float4* zw = (float4*)(Zw + lane * 20);
            zw[0] = make_float4(Zrp[0].x, Zrp[0].y, Zrp[1].x, Zrp[1].y);
            zw[1] = make_float4(Zrp[2].x, Zrp[2].y, Zrp[3].x, Zrp[3].y);
            zw[2] = make_float4(Zrp[4].x, Zrp[4].y, Zrp[5].x, Zrp[5].y);
            zw[3] = make_float4(Zrp[6].x, Zrp[6].y, Zrp[7].x, Zrp[7].y);
        }

        vv = vnext;
        crP = crN;
        czP = czN;
        tk = tkn;
        pairT = pairT1;
        pairT1 = pairT2;
    }

    // ---- peeled final step (t = 1022): tkn = query token sq[2047] ----
    {
        const int tkn = pairT.y;                    // pairT = {sq[2046], sq[2047]}
        const float4* zp = (const float4*)(Zw + tkn * 20);  // row written at iter 1021 (mask .y)
        const float4 e0 = zp[0], e1 = zp[1], e2 = zp[2], e3 = zp[3];
        const float cz = GAMMA * Gg[tk * 64 + tkn] + GAMMA;

        const v2f zero2 = {0.0f, 0.0f};
        v2f a2[8];
#pragma unroll
        for (int i = 0; i < 8; ++i) a2[i] = __builtin_elementwise_max(z2[i], zero2);
        v2f acc0 = a2[0] * W2p[0] + a2[1] * W2p[1];
        v2f acc1 = a2[2] * W2p[2] + a2[3] * W2p[3];
        v2f acc2 = a2[4] * W2p[4] + a2[5] * W2p[5];
        v2f acc3 = a2[6] * W2p[6] + a2[7] * W2p[7];
        v2f accv = (acc0 + acc1) + (acc2 + acc3);
        const float y = b2v + accv.x + accv.y;
        const float d = y - vv;

        const v2f d2 = {d, d};
        v2f p2[8];
#pragma unroll
        for (int i = 0; i < 8; ++i) p2[i] = W2p[i] * d2;
        const float sd = GAMMA * d;
        const v2f sd2 = {sd, sd};
        b2v -= sd;
#pragma unroll
        for (int i = 0; i < 8; ++i) W2p[i] = W2p[i] - sd2 * a2[i];

        float q[8];
#pragma unroll
        for (int j = 0; j < 8; ++j) {
            const float keep = bl0 ? PV(p2, j + 8) : PV(p2, j);
            const float give = bl0 ? PV(p2, j)     : PV(p2, j + 8);
            q[j] = keep + dppmov<0xB1>(give);
        }
        float r[4];
#pragma unroll
        for (int j = 0; j < 4; ++j) {
            const float keep = bl1 ? q[j + 4] : q[j];
            const float give = bl1 ? q[j]     : q[j + 4];
            r[j] = keep + dppmov<0x4E>(give);
        }
        float tot[4];
#pragma unroll
        for (int j = 0; j < 4; ++j) {
            float x = r[j] + dppmov<0x124>(r[j]);
            x = x + dppmov<0x128>(x);
            x = sum_x16(x);
            tot[j] = sum_x32(x);
        }
        float totm[4];
#pragma unroll
        for (int jj = 0; jj < 4; ++jj) {
            const float s0 = bl1 ? PV(a2, jj + 4)  : PV(a2, jj);
            const float s1 = bl1 ? PV(a2, jj + 12) : PV(a2, jj + 8);
            const float aenc = bl0 ? s1 : s0;
            totm[jj] = (aenc > 0.0f) ? tot[jj] : 0.0f;
        }
        float dz[16];
        dz[0]  = dppmov<0x00>(totm[0]);  dz[1]  = dppmov<0x00>(totm[1]);
        dz[2]  = dppmov<0x00>(totm[2]);  dz[3]  = dppmov<0x00>(totm[3]);
        dz[4]  = dppmov<0xAA>(totm[0]);  dz[5]  = dppmov<0xAA>(totm[1]);
        dz[6]  = dppmov<0xAA>(totm[2]);  dz[7]  = dppmov<0xAA>(totm[3]);
        dz[8]  = dppmov<0x55>(totm[0]);  dz[9]  = dppmov<0x55>(totm[1]);
        dz[10] = dppmov<0x55>(totm[2]);  dz[11] = dppmov<0x55>(totm[3]);
        dz[12] = dppmov<0xFF>(totm[0]);  dz[13] = dppmov<0xFF>(totm[1]);
        dz[14] = dppmov<0xFF>(totm[2]);  dz[15] = dppmov<0xFF>(totm[3]);

        const v2f cz2 = {cz, cz};
        const v2f zq2[8] = { {e0.x, e0.y}, {e0.z, e0.w}, {e1.x, e1.y}, {e1.z, e1.w},
                             {e2.x, e2.y}, {e2.z, e2.w}, {e3.x, e3.y}, {e3.z, e3.w} };
#pragma unroll
        for (int i = 0; i < 8; ++i) {
            v2f dzi = {dz[2 * i], dz[2 * i + 1]};
            z2[i] = zq2[i] - cz2 * dzi;
        }
    }

    // ---- final eval + per-wave output projection ----
    {
        const v2f zero2 = {0.0f, 0.0f};
        v2f acc = {0.0f, 0.0f};
#pragma unroll
        for (int i = 0; i < 8; ++i)
            acc = acc + __builtin_elementwise_max(z2[i], zero2) * W2p[i];
        ctxs[wv][lane] = b2v + acc.x + acc.y;
    }
    // same-wave DS in-order: ctx visible without barrier
    float o = outb[lane];
    for (int hh = 0; hh < 64; ++hh) o += ctxs[wv][hh] * outw[hh * 64 + lane];
    out[b * 64 + lane] = o;
}

// ---------------- launcher ----------------
extern "C" void kernel_launch(void* const* d_in, const int* in_sizes, int n_in,
                              void* d_out, int out_size, void* d_ws, size_t ws_size,
                              hipStream_t stream) {
    const int*   seq   = (const int*)d_in[0];
    const float* embed = (const float*)d_in[1];
    const float* ffw1  = (const float*)d_in[2];
    const float* ffb1  = (const float*)d_in[3];
    const float* ffw2  = (const float*)d_in[4];
    const float* ffb2  = (const float*)d_in[5];
    const float* lng   = (const float*)d_in[6];
    const float* lnb   = (const float*)d_in[7];
    const float* w1    = (const float*)d_in[8];
    const float* b1    = (const float*)d_in[9];
    const float* w2    = (const float*)d_in[10];
    const float* b2    = (const float*)d_in[11];
    const float* outw  = (const float*)d_in[12];
    const float* outb  = (const float*)d_in[13];
    float* ws  = (float*)d_ws;
    float* out = (float*)d_out;

    hipLaunchKernelGGL(hs_kernel, dim3(64), dim3(128), 0, stream,
                       embed, ffw1, ffb1, ffw2, ffb2, lng, lnb, ws);
    hipLaunchKernelGGL(gz_kernel, dim3(64), dim3(64), 0, stream, w1, b1, ws);
    hipLaunchKernelGGL(ttt_kernel, dim3(32), dim3(512), 0, stream,
                       seq, w2, b2, outw, outb, ws, out);
}

// Round 8
// 469.766 us; speedup vs baseline: 1.8737x; 1.8737x over previous
//
#include <hip/hip_runtime.h>

#define TSTEPS 1023
#define GAMMA  (0.01f / 32.0f)   // LR * dL/dy scale: 2/(64*2) folded
#define EPSV   1e-5f

// workspace layout (float offsets)
#define WS_HS 0       // 64*64 hs table
#define WS_G  4096    // 64*64 gram
#define WS_Z0 8192    // 64*16 initial Ztilde = hs@w1 + b1

typedef float v2f __attribute__((ext_vector_type(2)));
typedef unsigned int v2u __attribute__((ext_vector_type(2)));

template<int CTRL>
__device__ __forceinline__ float dppmov(float x) {
    return __int_as_float(__builtin_amdgcn_update_dpp(0, __float_as_int(x), CTRL, 0xF, 0xF, true));
}
// sum over {l, l^16} / {l, l^32} via permlane swaps (VALU, no DS)
__device__ __forceinline__ float sum_x16(float x) {
    v2u r = __builtin_amdgcn_permlane16_swap(__float_as_uint(x), __float_as_uint(x), false, false);
    return __uint_as_float(r[0]) + __uint_as_float(r[1]);
}
__device__ __forceinline__ float sum_x32(float x) {
    v2u r = __builtin_amdgcn_permlane32_swap(__float_as_uint(x), __float_as_uint(x), false, false);
    return __uint_as_float(r[0]) + __uint_as_float(r[1]);
}

// ---------------- kernel A: hs table (per-token embed->FFN->LN) ----------------
__global__ void hs_kernel(const float* __restrict__ embed,
                          const float* __restrict__ ffw1, const float* __restrict__ ffb1,
                          const float* __restrict__ ffw2, const float* __restrict__ ffb2,
                          const float* __restrict__ lng,  const float* __restrict__ lnb,
                          float* __restrict__ ws) {
    __shared__ float e[64];
    __shared__ float a1[128];
    int w = blockIdx.x;
    int tid = threadIdx.x;
    if (tid < 64) e[tid] = embed[w * 64 + tid];
    __syncthreads();
    float z1 = ffb1[tid];
    for (int x = 0; x < 64; ++x) z1 += e[x] * ffw1[x * 128 + tid];
    a1[tid] = fmaxf(z1, 0.0f);
    __syncthreads();
    if (tid < 64) {
        float f = ffb2[tid];
        for (int i = 0; i < 128; ++i) f += a1[i] * ffw2[i * 64 + tid];
        float hv = e[tid] + f;
        float s = hv;
#pragma unroll
        for (int m = 32; m >= 1; m >>= 1) s += __shfl_xor(s, m);
        float mu = s * (1.0f / 64.0f);
        float dv = hv - mu;
        float vs = dv * dv;
#pragma unroll
        for (int m = 32; m >= 1; m >>= 1) vs += __shfl_xor(vs, m);
        float rstd = 1.0f / sqrtf(vs * (1.0f / 64.0f) + EPSV);
        ws[WS_HS + w * 64 + tid] = dv * rstd * lng[tid] + lnb[tid];
    }
}

// ---------------- kernel B: Gram matrix + Ztilde0 ----------------
__global__ void gz_kernel(const float* __restrict__ w1, const float* __restrict__ b1,
                          float* __restrict__ ws) {
    __shared__ float row[64];
    int w = blockIdx.x, tid = threadIdx.x;
    row[tid] = ws[WS_HS + w * 64 + tid];
    __syncthreads();
    float g = 0.0f;
    for (int x = 0; x < 64; ++x) g += row[x] * ws[WS_HS + tid * 64 + x];
    ws[WS_G + w * 64 + tid] = g;
    if (tid < 16) {
        float z = b1[tid];
        for (int x = 0; x < 64; ++x) z += row[x] * w1[x * 16 + tid];
        ws[WS_Z0 + w * 16 + tid] = z;
    }
}

// scalar view of packed v2f array
#define PV(arr, j) (((j) & 1) ? arr[(j) >> 1].y : arr[(j) >> 1].x)

// ---------------- main kernel: per-batch sequential TTT scan ----------------
// one wave per batch. lane h owns W2[:,h], b2_h, Ztilde row h.
// XOR-PERMUTED register layout: lane l's slot s holds logical j = s ^ P(l),
// P = 8*b0 + 4*b1. This makes the xor1/xor2 folds select-free, the mask
// input trivially a2[jj], and the broadcast a set of XOR quad_perms (slots
// 0-3 identity). LDS Ztilde rows stay in LOGICAL order; the permutation is
// pure address arithmetic on chunked b128 reads/writes (chunk C <-> C^K,
// K = 2*b0 + b1, within-chunk order preserved).
__launch_bounds__(64, 1)
__global__ void ttt_kernel(const int* __restrict__ seq,
                           const float* __restrict__ w2, const float* __restrict__ b2i,
                           const float* __restrict__ outw, const float* __restrict__ outb,
                           const float* __restrict__ ws, float* __restrict__ out) {
    __shared__ float hs[64 * 64];
    __shared__ float G[64 * 64];
    __shared__ int   sq[2048];
    __shared__ __align__(16) float Z[64 * 20];   // logical order, row stride 20
    __shared__ float ctxbuf[64];

    const int b    = blockIdx.x;
    const int lane = threadIdx.x;

    const int P = ((lane & 1) << 3) | ((lane & 2) << 1);   // 8*b0 + 4*b1
    const int K = ((lane & 1) << 1) | ((lane >> 1) & 1);   // 2*b0 + b1 (chunk xor)
    const int ro0 = (0 ^ K) << 2;   // per-lane chunk offsets in floats
    const int ro1 = (1 ^ K) << 2;
    const int ro2 = (2 ^ K) << 2;
    const int ro3 = (3 ^ K) << 2;

    {   // vectorized staging (logical order)
        float4*       hv = (float4*)hs;
        const float4* sv = (const float4*)(ws + WS_HS);
#pragma unroll
        for (int m = 0; m < 16; ++m) hv[m * 64 + lane] = sv[m * 64 + lane];
        float4*       gv = (float4*)G;
        const float4* gs = (const float4*)(ws + WS_G);
#pragma unroll
        for (int m = 0; m < 16; ++m) gv[m * 64 + lane] = gs[m * 64 + lane];
        int4*       qv = (int4*)sq;
        const int4* qs = (const int4*)(seq + b * 2048);
#pragma unroll
        for (int m = 0; m < 8; ++m) qv[m * 64 + lane] = qs[m * 64 + lane];
        // Z0 rows to LDS (logical)
        const float4* z0 = (const float4*)(ws + WS_Z0 + lane * 16);
        float4* zr = (float4*)(Z + lane * 20);
        zr[0] = z0[0]; zr[1] = z0[1]; zr[2] = z0[2]; zr[3] = z0[3];
    }

    // W2 in permuted slot order: slot s <- logical s ^ P
    v2f W2p[8], Zrp[8], z2[8];
#pragma unroll
    for (int i = 0; i < 8; ++i) {
        const int m = (2 * i) ^ P;          // even, pair-preserving (P multiple of 4)
        v2f w;
        w.x = w2[m * 64 + lane];
        w.y = w2[(m + 1) * 64 + lane];
        W2p[i] = w;
    }
    float b2v = b2i[lane];
    __syncthreads();

    // Zrp = permuted read of own row; z2 = permuted read of row tk0
    {
        const float* zb = Z + lane * 20;
        const float4 c0 = *(const float4*)(zb + ro0);
        const float4 c1 = *(const float4*)(zb + ro1);
        const float4 c2 = *(const float4*)(zb + ro2);
        const float4 c3 = *(const float4*)(zb + ro3);
        Zrp[0] = {c0.x, c0.y}; Zrp[1] = {c0.z, c0.w};
        Zrp[2] = {c1.x, c1.y}; Zrp[3] = {c1.z, c1.w};
        Zrp[4] = {c2.x, c2.y}; Zrp[5] = {c2.z, c2.w};
        Zrp[6] = {c3.x, c3.y}; Zrp[7] = {c3.z, c3.w};
    }
    int tk = sq[0];
    {
        const float* zb = Z + tk * 20;
        const float4 c0 = *(const float4*)(zb + ro0);
        const float4 c1 = *(const float4*)(zb + ro1);
        const float4 c2 = *(const float4*)(zb + ro2);
        const float4 c3 = *(const float4*)(zb + ro3);
        z2[0] = {c0.x, c0.y}; z2[1] = {c0.z, c0.w};
        z2[2] = {c1.x, c1.y}; z2[3] = {c1.z, c1.w};
        z2[4] = {c2.x, c2.y}; z2[5] = {c2.z, c2.w};
        z2[6] = {c3.x, c3.y}; z2[7] = {c3.z, c3.w};
    }
    float vv = hs[sq[1] * 64 + lane];

    // precomputed write pointers: slot chunk C -> logical chunk C^K of own row
    float4* const wp0 = (float4*)(Z + lane * 20 + ro0);
    float4* const wp1 = (float4*)(Z + lane * 20 + ro1);
    float4* const wp2 = (float4*)(Z + lane * 20 + ro2);
    float4* const wp3 = (float4*)(Z + lane * 20 + ro3);

    int2 pairT  = *(const int2*)(sq + 2);
    int2 pairT1 = *(const int2*)(sq + 4);

    // main loop: steps 0..1021 (last step peeled)
#pragma unroll 2
    for (int t = 0; t < TSTEPS - 1; ++t) {
        const int tkn = pairT.x;
        const int tvn = pairT.y;

        // ---- DS reads (reg addresses, consumed late) ----
        const float* zb = Z + tkn * 20;           // Ztilde_t[tk(t+1)], permuted chunks
        const float4 e0 = *(const float4*)(zb + ro0);
        const float4 e1 = *(const float4*)(zb + ro1);
        const float4 e2 = *(const float4*)(zb + ro2);
        const float4 e3 = *(const float4*)(zb + ro3);
        const float vnext = hs[tvn * 64 + lane];
        const float cr = GAMMA * G[tk * 64 + lane] + GAMMA;
        const float cz = GAMMA * G[tk * 64 + tkn] + GAMMA;
        const int   lbase = (t < TSTEPS - 3) ? (2 * t + 6) : 2046;
        const int2  pairT2 = *(const int2*)(sq + lbase);

        // ---- forward (packed, slot order == logical sum) ----
        const v2f zero2 = {0.0f, 0.0f};
        v2f a2[8];
#pragma unroll
        for (int i = 0; i < 8; ++i) a2[i] = __builtin_elementwise_max(z2[i], zero2);
        v2f acc0 = a2[0] * W2p[0] + a2[1] * W2p[1];
        v2f acc1 = a2[2] * W2p[2] + a2[3] * W2p[3];
        v2f acc2 = a2[4] * W2p[4] + a2[5] * W2p[5];
        v2f acc3 = a2[6] * W2p[6] + a2[7] * W2p[7];
        v2f accv = (acc0 + acc1) + (acc2 + acc3);
        const float y = b2v + accv.x + accv.y;
        const float d = y - vv;

        // ---- p (pre-update W2) + local W2/b2 update ----
        const v2f d2 = {d, d};
        v2f p2[8];
#pragma unroll
        for (int i = 0; i < 8; ++i) p2[i] = W2p[i] * d2;
        const float sd = GAMMA * d;
        const v2f sd2 = {sd, sd};
        b2v -= sd;
#pragma unroll
        for (int i = 0; i < 8; ++i) W2p[i] = W2p[i] - sd2 * a2[i];

        // ---- reduction: SELECT-FREE folds (permuted layout aligns operands) ----
        float q[8];
#pragma unroll
        for (int j = 0; j < 8; ++j)
            q[j] = PV(p2, j) + dppmov<0xB1>(PV(p2, j + 8));   // xor1 pair-fold
        float r[4];
#pragma unroll
        for (int j = 0; j < 4; ++j)
            r[j] = q[j] + dppmov<0x4E>(q[j + 4]);             // xor2 pair-fold
        float tot[4];
#pragma unroll
        for (int j = 0; j < 4; ++j) {
            float x = r[j] + dppmov<0x124>(r[j]);             // row_ror:4
            x = x + dppmov<0x128>(x);                         // row_ror:8
            x = sum_x16(x);
            tot[j] = sum_x32(x);
        }
        // tot[jj](l) = da[jj + P(l)], replicated across quads

        // ---- mask (encoded: a_slot[jj] IS a[jj+P]) ----
        float totm[4];
#pragma unroll
        for (int jj = 0; jj < 4; ++jj)
            totm[jj] = (PV(a2, jj) > 0.0f) ? tot[jj] : 0.0f;

        // ---- broadcast into permuted slots: XOR quad_perms; slots 0-3 identity ----
        float dzs[16];
        dzs[0] = totm[0]; dzs[1] = totm[1]; dzs[2] = totm[2]; dzs[3] = totm[3];
#pragma unroll
        for (int j = 0; j < 4; ++j) dzs[4 + j]  = dppmov<0x4E>(totm[j]);  // pos^2
#pragma unroll
        for (int j = 0; j < 4; ++j) dzs[8 + j]  = dppmov<0xB1>(totm[j]);  // pos^1
#pragma unroll
        for (int j = 0; j < 4; ++j) dzs[12 + j] = dppmov<0x1B>(totm[j]);  // pos^3

        v2f dz2[8];
#pragma unroll
        for (int i = 0; i < 8; ++i) dz2[i] = {dzs[2 * i], dzs[2 * i + 1]};

        // ---- apply (slot order throughout) ----
        const v2f cr2 = {cr, cr}, cz2 = {cz, cz};
        const v2f zq2[8] = { {e0.x, e0.y}, {e0.z, e0.w}, {e1.x, e1.y}, {e1.z, e1.w},
                             {e2.x, e2.y}, {e2.z, e2.w}, {e3.x, e3.y}, {e3.z, e3.w} };
#pragma unroll
        for (int i = 0; i < 8; ++i) {
            Zrp[i] = Zrp[i] - cr2 * dz2[i];
            z2[i]  = zq2[i] - cz2 * dz2[i];
        }
        // writeback own row: slot chunk C -> logical chunk C^K (precomputed ptrs)
        *wp0 = make_float4(Zrp[0].x, Zrp[0].y, Zrp[1].x, Zrp[1].y);
        *wp1 = make_float4(Zrp[2].x, Zrp[2].y, Zrp[3].x, Zrp[3].y);
        *wp2 = make_float4(Zrp[4].x, Zrp[4].y, Zrp[5].x, Zrp[5].y);
        *wp3 = make_float4(Zrp[6].x, Zrp[6].y, Zrp[7].x, Zrp[7].y);

        vv = vnext;
        tk = tkn;
        pairT = pairT1;
        pairT1 = pairT2;
    }

    // ---- peeled final step (t = 1022): tkn = query token sq[2047] ----
    {
        const int tkn = pairT.y;                  // pairT = {sq[2046], sq[2047]}
        const float* zb = Z + tkn * 20;
        const float4 e0 = *(const float4*)(zb + ro0);
        const float4 e1 = *(const float4*)(zb + ro1);
        const float4 e2 = *(const float4*)(zb + ro2);
        const float4 e3 = *(const float4*)(zb + ro3);
        const float cz = GAMMA * G[tk * 64 + tkn] + GAMMA;

        const v2f zero2 = {0.0f, 0.0f};
        v2f a2[8];
#pragma unroll
        for (int i = 0; i < 8; ++i) a2[i] = __builtin_elementwise_max(z2[i], zero2);
        v2f acc0 = a2[0] * W2p[0] + a2[1] * W2p[1];
        v2f acc1 = a2[2] * W2p[2] + a2[3] * W2p[3];
        v2f acc2 = a2[4] * W2p[4] + a2[5] * W2p[5];
        v2f acc3 = a2[6] * W2p[6] + a2[7] * W2p[7];
        v2f accv = (acc0 + acc1) + (acc2 + acc3);
        const float y = b2v + accv.x + accv.y;
        const float d = y - vv;

        const v2f d2 = {d, d};
        v2f p2[8];
#pragma unroll
        for (int i = 0; i < 8; ++i) p2[i] = W2p[i] * d2;
        const float sd = GAMMA * d;
        const v2f sd2 = {sd, sd};
        b2v -= sd;
#pragma unroll
        for (int i = 0; i < 8; ++i) W2p[i] = W2p[i] - sd2 * a2[i];

        float q[8];
#pragma unroll
        for (int j = 0; j < 8; ++j)
            q[j] = PV(p2, j) + dppmov<0xB1>(PV(p2, j + 8));
        float r[4];
#pragma unroll
        for (int j = 0; j < 4; ++j)
            r[j] = q[j] + dppmov<0x4E>(q[j + 4]);
        float tot[4];
#pragma unroll
        for (int j = 0; j < 4; ++j) {
            float x = r[j] + dppmov<0x124>(r[j]);
            x = x + dppmov<0x128>(x);
            x = sum_x16(x);
            tot[j] = sum_x32(x);
        }
        float totm[4];
#pragma unroll
        for (int jj = 0; jj < 4; ++jj)
            totm[jj] = (PV(a2, jj) > 0.0f) ? tot[jj] : 0.0f;
        float dzs[16];
        dzs[0] = totm[0]; dzs[1] = totm[1]; dzs[2] = totm[2]; dzs[3] = totm[3];
#pragma unroll
        for (int j = 0; j < 4; ++j) dzs[4 + j]  = dppmov<0x4E>(totm[j]);
#pragma unroll
        for (int j = 0; j < 4; ++j) dzs[8 + j]  = dppmov<0xB1>(totm[j]);
#pragma unroll
        for (int j = 0; j < 4; ++j) dzs[12 + j] = dppmov<0x1B>(totm[j]);

        const v2f cz2 = {cz, cz};
        const v2f zq2[8] = { {e0.x, e0.y}, {e0.z, e0.w}, {e1.x, e1.y}, {e1.z, e1.w},
                             {e2.x, e2.y}, {e2.z, e2.w}, {e3.x, e3.y}, {e3.z, e3.w} };
#pragma unroll
        for (int i = 0; i < 8; ++i) {
            v2f dzi = {dzs[2 * i], dzs[2 * i + 1]};
            z2[i] = zq2[i] - cz2 * dzi;
        }
    }

    // ---- final eval: ctx = relu(z_final)@W2_f + b2_f (order-free sum) ----
    {
        const v2f zero2 = {0.0f, 0.0f};
        v2f acc = {0.0f, 0.0f};
#pragma unroll
        for (int i = 0; i < 8; ++i)
            acc = acc + __builtin_elementwise_max(z2[i], zero2) * W2p[i];
        ctxbuf[lane] = b2v + acc.x + acc.y;
    }
    __syncthreads();

    float o = outb[lane];
    for (int hh = 0; hh < 64; ++hh) o += ctxbuf[hh] * outw[hh * 64 + lane];
    out[b * 64 + lane] = o;
}

// ---------------- launcher ----------------
extern "C" void kernel_launch(void* const* d_in, const int* in_sizes, int n_in,
                              void* d_out, int out_size, void* d_ws, size_t ws_size,
                              hipStream_t stream) {
    const int*   seq   = (const int*)d_in[0];
    const float* embed = (const float*)d_in[1];
    const float* ffw1  = (const float*)d_in[2];
    const float* ffb1  = (const float*)d_in[3];
    const float* ffw2  = (const float*)d_in[4];
    const float* ffb2  = (const float*)d_in[5];
    const float* lng   = (const float*)d_in[6];
    const float* lnb   = (const float*)d_in[7];
    const float* w1    = (const float*)d_in[8];
    const float* b1    = (const float*)d_in[9];
    const float* w2    = (const float*)d_in[10];
    const float* b2    = (const float*)d_in[11];
    const float* outw  = (const float*)d_in[12];
    const float* outb  = (const float*)d_in[13];
    float* ws  = (float*)d_ws;
    float* out = (float*)d_out;

    hipLaunchKernelGGL(hs_kernel, dim3(64), dim3(128), 0, stream,
                       embed, ffw1, ffb1, ffw2, ffb2, lng, lnb, ws);
    hipLaunchKernelGGL(gz_kernel, dim3(64), dim3(64), 0, stream, w1, b1, ws);
    hipLaunchKernelGGL(ttt_kernel, dim3(256), dim3(64), 0, stream,
                       seq, w2, b2, outw, outb, ws, out);
}

// Round 9
// 457.809 us; speedup vs baseline: 1.9226x; 1.0261x over previous
//
#include <hip/hip_runtime.h>

#define TSTEPS 1023
#define GAMMA  (0.01f / 32.0f)   // LR * dL/dy scale: 2/(64*2) folded
#define EPSV   1e-5f

// workspace layout (float offsets)
#define WS_HS 0       // 64*64 hs table
#define WS_G  4096    // 64*64 PRE-SCALED gram: Gs = GAMMA*G + GAMMA
#define WS_Z0 8192    // 64*16 initial Ztilde = hs@w1 + b1

typedef float v2f __attribute__((ext_vector_type(2)));
typedef unsigned int v2u __attribute__((ext_vector_type(2)));

template<int CTRL>
__device__ __forceinline__ float dppmov(float x) {
    return __int_as_float(__builtin_amdgcn_update_dpp(0, __float_as_int(x), CTRL, 0xF, 0xF, true));
}
__device__ __forceinline__ v2u swap16(float a, float b) {
    return __builtin_amdgcn_permlane16_swap(__float_as_uint(a), __float_as_uint(b), false, false);
}
__device__ __forceinline__ v2u swap32(float a, float b) {
    return __builtin_amdgcn_permlane32_swap(__float_as_uint(a), __float_as_uint(b), false, false);
}
#define U2F(x) __uint_as_float(x)

// ---------------- fused preprocessing kernel (single block) ----------------
// Computes hs table (embed->FFN->LN), PRE-SCALED Gram Gs = gamma*(hs hs^T)+gamma,
// and Z0 = hs@w1 + b1.  One 1024-thread block, weights staged in LDS (<64KB).
__launch_bounds__(1024, 1)
__global__ void prep_kernel(const float* __restrict__ embed,
                            const float* __restrict__ ffw1, const float* __restrict__ ffb1,
                            const float* __restrict__ ffw2, const float* __restrict__ ffb2,
                            const float* __restrict__ lng,  const float* __restrict__ lnb,
                            const float* __restrict__ w1,   const float* __restrict__ b1,
                            float* __restrict__ ws) {
    __shared__ float sE[64 * 64];     // embed; h in-place after phase B
    __shared__ float sA[64 * 128];    // a1; hs reuses first 4096 after phase C
    __shared__ float sB1[128];
    __shared__ float sB2[64], sLG[64], sLB[64];

    const int tid = threadIdx.x;

    {   // stage embed + biases
        float4* d = (float4*)sE; const float4* s = (const float4*)embed;
        d[tid & 1023] = s[tid & 1023];        // 1024 float4 = 4096 floats
        if (tid < 128) sB1[tid] = ffb1[tid];
        if (tid < 64) { sB2[tid] = ffb2[tid]; sLG[tid] = lng[tid]; sLB[tid] = lnb[tid]; }
    }
    __syncthreads();

    // phase A: a1[w][i] = relu(e[w]@ff_w1 + b1), 8192 cells
    for (int c = tid; c < 8192; c += 1024) {
        const int w = c >> 7, i = c & 127;
        float z = sB1[i];
        const float* er = sE + w * 64;
        for (int x = 0; x < 64; ++x) z += er[x] * ffw1[x * 128 + i];
        sA[c] = fmaxf(z, 0.0f);
    }
    __syncthreads();

    // phase B: h[w][d] = e + a1[w]@ff_w2 + b2, in place over sE
    for (int c = tid; c < 4096; c += 1024) {
        const int w = c >> 6, d0 = c & 63;
        float f = sB2[d0];
        const float* ar = sA + w * 128;
        for (int i = 0; i < 128; ++i) f += ar[i] * ffw2[i * 64 + d0];
        sE[c] += f;
    }
    __syncthreads();

    // phase C: LayerNorm per token -> hs into sA[0..4095] and global ws
    {
        const int wv = tid >> 6, lane = tid & 63;
        for (int w = wv; w < 64; w += 16) {
            float hv = sE[w * 64 + lane];
            float s = hv;
#pragma unroll
            for (int m = 32; m >= 1; m >>= 1) s += __shfl_xor(s, m);
            float mu = s * (1.0f / 64.0f);
            float dv = hv - mu;
            float vs = dv * dv;
#pragma unroll
            for (int m = 32; m >= 1; m >>= 1) vs += __shfl_xor(vs, m);
            float rstd = 1.0f / sqrtf(vs * (1.0f / 64.0f) + EPSV);
            float o = dv * rstd * sLG[lane] + sLB[lane];
            sA[w * 64 + lane] = o;
            ws[WS_HS + w * 64 + lane] = o;
        }
    }
    __syncthreads();

    // phase D: Gs (pre-scaled) + Z0
    for (int c = tid; c < 4096; c += 1024) {
        const int w = c >> 6, x = c & 63;
        const float* r0 = sA + w * 64;
        const float* r1 = sA + x * 64;
        float g = 0.0f;
        for (int t = 0; t < 64; ++t) g += r0[t] * r1[t];
        ws[WS_G + c] = GAMMA * g + GAMMA;
    }
    {
        const int c = tid;   // exactly 1024 cells
        const int w = c >> 4, j = c & 15;
        float z = b1[j];
        const float* r = sA + w * 64;
        for (int x = 0; x < 64; ++x) z += r[x] * w1[x * 16 + j];
        ws[WS_Z0 + c] = z;
    }
}

// scalar view of packed v2f array
#define PV(arr, j) (((j) & 1) ? arr[(j) >> 1].y : arr[(j) >> 1].x)

// ---------------- main kernel: per-batch sequential TTT scan ----------------
// one wave per batch; XOR-permuted slot layout (P = 8*b0 + 4*b1, chunk xor
// K = 2*b0 + b1).  Reduction: select-free quad_perm folds (xor1,xor2) ->
// mask at r (slot-aligned) -> row_ror:4/8 orbit sums -> permlane16/32
// PAIR-swap combine (6 ops, full 64-lane sums of all 4 values) ->
// swap-based re-replicate (6 ops; swap-direction ambiguity cancels) ->
// quad_perm broadcast.  Gs table pre-scaled (no fma for cr/cz).
struct TTTSmem {
    float hs[4096];
    float Gs[4096];
    int   sq[2048];               // unguarded prefetch reads sq[2048..2049] -> lands in Z[0..1] (harmless)
    __align__(16) float Z[64 * 20 + 8];
    float ctx[64];
};

__launch_bounds__(64, 1)
__global__ void ttt_kernel(const int* __restrict__ seq,
                           const float* __restrict__ w2, const float* __restrict__ b2i,
                           const float* __restrict__ outw, const float* __restrict__ outb,
                           const float* __restrict__ ws, float* __restrict__ out) {
    __shared__ TTTSmem sm;

    const int b    = blockIdx.x;
    const int lane = threadIdx.x;

    const int P = ((lane & 1) << 3) | ((lane & 2) << 1);   // 8*b0 + 4*b1
    const int K = ((lane & 1) << 1) | ((lane >> 1) & 1);   // 2*b0 + b1 (chunk xor)
    const int ro0 = (0 ^ K) << 2;
    const int ro1 = (1 ^ K) << 2;
    const int ro2 = (2 ^ K) << 2;
    const int ro3 = (3 ^ K) << 2;

    {   // vectorized staging
        float4*       hv = (float4*)sm.hs;
        const float4* sv = (const float4*)(ws + WS_HS);
#pragma unroll
        for (int m = 0; m < 16; ++m) hv[m * 64 + lane] = sv[m * 64 + lane];
        float4*       gv = (float4*)sm.Gs;
        const float4* gs = (const float4*)(ws + WS_G);
#pragma unroll
        for (int m = 0; m < 16; ++m) gv[m * 64 + lane] = gs[m * 64 + lane];
        int4*       qv = (int4*)sm.sq;
        const int4* qs = (const int4*)(seq + b * 2048);
#pragma unroll
        for (int m = 0; m < 8; ++m) qv[m * 64 + lane] = qs[m * 64 + lane];
        const float4* z0 = (const float4*)(ws + WS_Z0 + lane * 16);
        float4* zr = (float4*)(sm.Z + lane * 20);
        zr[0] = z0[0]; zr[1] = z0[1]; zr[2] = z0[2]; zr[3] = z0[3];
    }

    // W2 in permuted slot order: slot s <- logical s ^ P
    v2f W2p[8], z2[8];
#pragma unroll
    for (int i = 0; i < 8; ++i) {
        const int m = (2 * i) ^ P;
        v2f w;
        w.x = w2[m * 64 + lane];
        w.y = w2[(m + 1) * 64 + lane];
        W2p[i] = w;
    }
    float b2v = b2i[lane];
    __syncthreads();

    // Zr = permuted read of own row (as float4 chunks); z2 = permuted read of row tk0
    float4 ZrQ[4];
    v2f* Zv = (v2f*)ZrQ;
    {
        const float* zb = sm.Z + lane * 20;
        ZrQ[0] = *(const float4*)(zb + ro0);
        ZrQ[1] = *(const float4*)(zb + ro1);
        ZrQ[2] = *(const float4*)(zb + ro2);
        ZrQ[3] = *(const float4*)(zb + ro3);
    }
    int tk = sm.sq[0];
    {
        const float* zb = sm.Z + tk * 20;
        const float4 c0 = *(const float4*)(zb + ro0);
        const float4 c1 = *(const float4*)(zb + ro1);
        const float4 c2 = *(const float4*)(zb + ro2);
        const float4 c3 = *(const float4*)(zb + ro3);
        z2[0] = {c0.x, c0.y}; z2[1] = {c0.z, c0.w};
        z2[2] = {c1.x, c1.y}; z2[3] = {c1.z, c1.w};
        z2[4] = {c2.x, c2.y}; z2[5] = {c2.z, c2.w};
        z2[6] = {c3.x, c3.y}; z2[7] = {c3.z, c3.w};
    }
    float vv = sm.hs[sm.sq[1] * 64 + lane];

    float4* const wp0 = (float4*)(sm.Z + lane * 20 + ro0);
    float4* const wp1 = (float4*)(sm.Z + lane * 20 + ro1);
    float4* const wp2 = (float4*)(sm.Z + lane * 20 + ro2);
    float4* const wp3 = (float4*)(sm.Z + lane * 20 + ro3);

    int2 pairT  = *(const int2*)(sm.sq + 2);
    int2 pairT1 = *(const int2*)(sm.sq + 4);

    // main loop: steps 0..1021 (last step peeled)
#pragma unroll 2
    for (int t = 0; t < TSTEPS - 1; ++t) {
        const int tkn = pairT.x;
        const int tvn = pairT.y;

        // ---- DS reads (reg addresses, consumed late) ----
        const float* zb = sm.Z + tkn * 20;
        const float4 e0 = *(const float4*)(zb + ro0);
        const float4 e1 = *(const float4*)(zb + ro1);
        const float4 e2 = *(const float4*)(zb + ro2);
        const float4 e3 = *(const float4*)(zb + ro3);
        const float vnext = sm.hs[tvn * 64 + lane];
        const float cr = sm.Gs[tk * 64 + lane];     // pre-scaled: gamma*(G+1)
        const float cz = sm.Gs[tk * 64 + tkn];
        const int2 pairT2 = *(const int2*)(sm.sq + 2 * t + 6);  // t=1021 reads Z[0..1]: unused

        // ---- forward ----
        const v2f zero2 = {0.0f, 0.0f};
        v2f a2[8];
#pragma unroll
        for (int i = 0; i < 8; ++i) a2[i] = __builtin_elementwise_max(z2[i], zero2);
        v2f acc0 = a2[0] * W2p[0] + a2[1] * W2p[1];
        v2f acc1 = a2[2] * W2p[2] + a2[3] * W2p[3];
        v2f acc2 = a2[4] * W2p[4] + a2[5] * W2p[5];
        v2f acc3 = a2[6] * W2p[6] + a2[7] * W2p[7];
        v2f accv = (acc0 + acc1) + (acc2 + acc3);
        const float y = b2v + accv.x + accv.y;
        const float d = y - vv;

        // ---- p (pre-update W2) + local W2/b2 update ----
        const v2f d2 = {d, d};
        v2f p2[8];
#pragma unroll
        for (int i = 0; i < 8; ++i) p2[i] = W2p[i] * d2;
        const float sd = GAMMA * d;
        const v2f sd2 = {sd, sd};
        b2v -= sd;
#pragma unroll
        for (int i = 0; i < 8; ++i) W2p[i] = W2p[i] - sd2 * a2[i];

        // ---- reduction: select-free folds over lane bits 0,1 ----
        float q[8];
#pragma unroll
        for (int j = 0; j < 8; ++j)
            q[j] = PV(p2, j) + dppmov<0xB1>(PV(p2, j + 8));
        float r[4];
#pragma unroll
        for (int j = 0; j < 4; ++j)
            r[j] = q[j] + dppmov<0x4E>(q[j + 4]);

        // ---- mask at r (slot-aligned, wave-uniform per logical; commutes with sums) ----
        float rm[4];
        rm[0] = (a2[0].x > 0.0f) ? r[0] : 0.0f;
        rm[1] = (a2[0].y > 0.0f) ? r[1] : 0.0f;
        rm[2] = (a2[1].x > 0.0f) ? r[2] : 0.0f;
        rm[3] = (a2[1].y > 0.0f) ? r[3] : 0.0f;

        // ---- orbit sums over lane bits 2,3 ----
#pragma unroll
        for (int j = 0; j < 4; ++j) {
            rm[j] = rm[j] + dppmov<0x124>(rm[j]);   // row_ror:4
            rm[j] = rm[j] + dppmov<0x128>(rm[j]);   // row_ror:8
        }

        // ---- pair-swap combine over bits 4,5 (6 ops) then re-replicate (6 ops) ----
        v2u f01 = swap16(rm[0], rm[1]);
        const float F  = U2F(f01[0]) + U2F(f01[1]);   // sx16(rm[b4]) row-interleaved
        v2u f23 = swap16(rm[2], rm[3]);
        const float F2 = U2F(f23[0]) + U2F(f23[1]);
        v2u g01 = swap32(F, F2);
        const float T  = U2F(g01[0]) + U2F(g01[1]);   // dz[(2b5+b4) ^ P] per lane
        v2u u01 = swap16(T, T);
        const float U0 = U2F(u01[0]);                 // dz[(2b5) ^ P]
        const float U1 = U2F(u01[1]);                 // dz[(2b5+1) ^ P]
        v2u v02 = swap32(U0, U0);
        v2u v13 = swap32(U1, U1);
        const float D0 = U2F(v02[0]);                 // dz[0 ^ P] (replicated)
        const float D2 = U2F(v02[1]);                 // dz[2 ^ P]
        const float D1 = U2F(v13[0]);                 // dz[1 ^ P]
        const float D3 = U2F(v13[1]);                 // dz[3 ^ P]

        // ---- broadcast into permuted slots: slots 0-3 identity, rest XOR quad_perms ----
        float dzs[16];
        dzs[0] = D0; dzs[1] = D1; dzs[2] = D2; dzs[3] = D3;
        dzs[4]  = dppmov<0x4E>(D0); dzs[5]  = dppmov<0x4E>(D1);
        dzs[6]  = dppmov<0x4E>(D2); dzs[7]  = dppmov<0x4E>(D3);
        dzs[8]  = dppmov<0xB1>(D0); dzs[9]  = dppmov<0xB1>(D1);
        dzs[10] = dppmov<0xB1>(D2); dzs[11] = dppmov<0xB1>(D3);
        dzs[12] = dppmov<0x1B>(D0); dzs[13] = dppmov<0x1B>(D1);
        dzs[14] = dppmov<0x1B>(D2); dzs[15] = dppmov<0x1B>(D3);

        v2f dz2[8];
#pragma unroll
        for (int i = 0; i < 8; ++i) dz2[i] = {dzs[2 * i], dzs[2 * i + 1]};

        // ---- apply ----
        const v2f cr2 = {cr, cr}, cz2 = {cz, cz};
        const v2f zq2[8] = { {e0.x, e0.y}, {e0.z, e0.w}, {e1.x, e1.y}, {e1.z, e1.w},
                             {e2.x, e2.y}, {e2.z, e2.w}, {e3.x, e3.y}, {e3.z, e3.w} };
#pragma unroll
        for (int i = 0; i < 8; ++i) {
            Zv[i]  = Zv[i]  - cr2 * dz2[i];
            z2[i]  = zq2[i] - cz2 * dz2[i];
        }
        *wp0 = ZrQ[0];
        *wp1 = ZrQ[1];
        *wp2 = ZrQ[2];
        *wp3 = ZrQ[3];

        vv = vnext;
        tk = tkn;
        pairT = pairT1;
        pairT1 = pairT2;
    }

    // ---- peeled final step (t = 1022): tkn = query token sq[2047] ----
    {
        const int tkn = pairT.y;                  // pairT = {sq[2046], sq[2047]}
        const float* zb = sm.Z + tkn * 20;
        const float4 e0 = *(const float4*)(zb + ro0);
        const float4 e1 = *(const float4*)(zb + ro1);
        const float4 e2 = *(const float4*)(zb + ro2);
        const float4 e3 = *(const float4*)(zb + ro3);
        const float cz = sm.Gs[tk * 64 + tkn];

        const v2f zero2 = {0.0f, 0.0f};
        v2f a2[8];
#pragma unroll
        for (int i = 0; i < 8; ++i) a2[i] = __builtin_elementwise_max(z2[i], zero2);
        v2f acc0 = a2[0] * W2p[0] + a2[1] * W2p[1];
        v2f acc1 = a2[2] * W2p[2] + a2[3] * W2p[3];
        v2f acc2 = a2[4] * W2p[4] + a2[5] * W2p[5];
        v2f acc3 = a2[6] * W2p[6] + a2[7] * W2p[7];
        v2f accv = (acc0 + acc1) + (acc2 + acc3);
        const float y = b2v + accv.x + accv.y;
        const float d = y - vv;

        const v2f d2 = {d, d};
        v2f p2[8];
#pragma unroll
        for (int i = 0; i < 8; ++i) p2[i] = W2p[i] * d2;
        const float sd = GAMMA * d;
        const v2f sd2 = {sd, sd};
        b2v -= sd;
#pragma unroll
        for (int i = 0; i < 8; ++i) W2p[i] = W2p[i] - sd2 * a2[i];

        float q[8];
#pragma unroll
        for (int j = 0; j < 8; ++j)
            q[j] = PV(p2, j) + dppmov<0xB1>(PV(p2, j + 8));
        float r[4];
#pragma unroll
        for (int j = 0; j < 4; ++j)
            r[j] = q[j] + dppmov<0x4E>(q[j + 4]);
        float rm[4];
        rm[0] = (a2[0].x > 0.0f) ? r[0] : 0.0f;
        rm[1] = (a2[0].y > 0.0f) ? r[1] : 0.0f;
        rm[2] = (a2[1].x > 0.0f) ? r[2] : 0.0f;
        rm[3] = (a2[1].y > 0.0f) ? r[3] : 0.0f;
#pragma unroll
        for (int j = 0; j < 4; ++j) {
            rm[j] = rm[j] + dppmov<0x124>(rm[j]);
            rm[j] = rm[j] + dppmov<0x128>(rm[j]);
        }
        v2u f01 = swap16(rm[0], rm[1]);
        const float F  = U2F(f01[0]) + U2F(f01[1]);
        v2u f23 = swap16(rm[2], rm[3]);
        const float F2 = U2F(f23[0]) + U2F(f23[1]);
        v2u g01 = swap32(F, F2);
        const float T  = U2F(g01[0]) + U2F(g01[1]);
        v2u u01 = swap16(T, T);
        const float U0 = U2F(u01[0]);
        const float U1 = U2F(u01[1]);
        v2u v02 = swap32(U0, U0);
        v2u v13 = swap32(U1, U1);
        const float D0 = U2F(v02[0]);
        const float D2 = U2F(v02[1]);
        const float D1 = U2F(v13[0]);
        const float D3 = U2F(v13[1]);

        float dzs[16];
        dzs[0] = D0; dzs[1] = D1; dzs[2] = D2; dzs[3] = D3;
        dzs[4]  = dppmov<0x4E>(D0); dzs[5]  = dppmov<0x4E>(D1);
        dzs[6]  = dppmov<0x4E>(D2); dzs[7]  = dppmov<0x4E>(D3);
        dzs[8]  = dppmov<0xB1>(D0); dzs[9]  = dppmov<0xB1>(D1);
        dzs[10] = dppmov<0xB1>(D2); dzs[11] = dppmov<0xB1>(D3);
        dzs[12] = dppmov<0x1B>(D0); dzs[13] = dppmov<0x1B>(D1);
        dzs[14] = dppmov<0x1B>(D2); dzs[15] = dppmov<0x1B>(D3);

        const v2f cz2 = {cz, cz};
        const v2f zq2[8] = { {e0.x, e0.y}, {e0.z, e0.w}, {e1.x, e1.y}, {e1.z, e1.w},
                             {e2.x, e2.y}, {e2.z, e2.w}, {e3.x, e3.y}, {e3.z, e3.w} };
#pragma unroll
        for (int i = 0; i < 8; ++i) {
            v2f dzi = {dzs[2 * i], dzs[2 * i + 1]};
            z2[i] = zq2[i] - cz2 * dzi;
        }
    }

    // ---- final eval: ctx = relu(z_final)@W2_f + b2_f (order-free sum) ----
    {
        const v2f zero2 = {0.0f, 0.0f};
        v2f acc = {0.0f, 0.0f};
#pragma unroll
        for (int i = 0; i < 8; ++i)
            acc = acc + __builtin_elementwise_max(z2[i], zero2) * W2p[i];
        sm.ctx[lane] = b2v + acc.x + acc.y;
    }
    __syncthreads();

    float o = outb[lane];
    for (int hh = 0; hh < 64; ++hh) o += sm.ctx[hh] * outw[hh * 64 + lane];
    out[b * 64 + lane] = o;
}

// ---------------- launcher ----------------
extern "C" void kernel_launch(void* const* d_in, const int* in_sizes, int n_in,
                              void* d_out, int out_size, void* d_ws, size_t ws_size,
                              hipStream_t stream) {
    const int*   seq   = (const int*)d_in[0];
    const float* embed = (const float*)d_in[1];
    const float* ffw1  = (const float*)d_in[2];
    const float* ffb1  = (const float*)d_in[3];
    const float* ffw2  = (const float*)d_in[4];
    const float* ffb2  = (const float*)d_in[5];
    const float* lng   = (const float*)d_in[6];
    const float* lnb   = (const float*)d_in[7];
    const float* w1    = (const float*)d_in[8];
    const float* b1    = (const float*)d_in[9];
    const float* w2    = (const float*)d_in[10];
    const float* b2    = (const float*)d_in[11];
    const float* outw  = (const float*)d_in[12];
    const float* outb  = (const float*)d_in[13];
    float* ws  = (float*)d_ws;
    float* out = (float*)d_out;

    hipLaunchKernelGGL(prep_kernel, dim3(1), dim3(1024), 0, stream,
                       embed, ffw1, ffb1, ffw2, ffb2, lng, lnb, w1, b1, ws);
    hipLaunchKernelGGL(ttt_kernel, dim3(256), dim3(64), 0, stream,
                       seq, w2, b2, outw, outb, ws, out);
}